// Round 2
// baseline (87958.252 us; speedup 1.0000x reference)
//
#include <hip/hip_runtime.h>
#include <hip/hip_bf16.h>
#include <math.h>

// LSTM decoder: B=64, T=512, IN=256, OUT=256, H=1024, 2 layers + linear head.
// Round 2: single persistent kernel, 256 blocks x 512 threads (1 per CU),
// weights pinned in VGPRs (block owns 16 gate-columns; 8 waves = 8-way K
// split, each wave loops the 4 M-strips reusing its B-frag), cell state in
// registers, h0/h1 exchanged via global with a custom hierarchical grid
// barrier (2 per step). Projection folded into phase A on blocks 0..15,
// issued between barrier-arrive and barrier-wait to overlap barrier latency.

typedef __attribute__((ext_vector_type(8))) short bf16x8;   // 8 x bf16
typedef __attribute__((ext_vector_type(4))) float f32x4;

__device__ __forceinline__ float sigm(float v) { return 1.f / (1.f + expf(-v)); }

// ---------------- prep kernels (one-time per launch) ----------------

// W0cat[u*4+g][k] : k<256 -> Wih0[g*1024+u][k], else Whh0[g*1024+u][k-256]
__global__ __launch_bounds__(256) void prep_w0(const float* __restrict__ Wih0,
                                               const float* __restrict__ Whh0,
                                               __hip_bfloat16* __restrict__ W0) {
  const unsigned n = 4096u * 1280u;
  for (unsigned d = blockIdx.x * blockDim.x + threadIdx.x; d < n;
       d += blockDim.x * gridDim.x) {
    unsigned r = d / 1280u;
    unsigned k = d - r * 1280u;
    unsigned u = r >> 2, g = r & 3u;
    unsigned srow = g * 1024u + u;
    float v = (k < 256u) ? Wih0[(size_t)srow * 256u + k]
                         : Whh0[(size_t)srow * 1024u + (k - 256u)];
    W0[d] = __float2bfloat16(v);
  }
}

// W1ext[4352][2048]: rows<4096 reordered LSTM1 weights [Wih1|Whh1];
// rows 4096+o: [zeros(1024) | Wlin[o]]
__global__ __launch_bounds__(256) void prep_w1(const float* __restrict__ Wih1,
                                               const float* __restrict__ Whh1,
                                               const float* __restrict__ Wlin,
                                               __hip_bfloat16* __restrict__ W1) {
  const unsigned n = 4352u * 2048u;
  for (unsigned d = blockIdx.x * blockDim.x + threadIdx.x; d < n;
       d += blockDim.x * gridDim.x) {
    unsigned r = d >> 11;
    unsigned k = d & 2047u;
    float v;
    if (r < 4096u) {
      unsigned u = r >> 2, g = r & 3u;
      unsigned srow = g * 1024u + u;
      v = (k < 1024u) ? Wih1[(size_t)srow * 1024u + k]
                      : Whh1[(size_t)srow * 1024u + (k - 1024u)];
    } else {
      unsigned o = r - 4096u;
      v = (k < 1024u) ? 0.f : Wlin[(size_t)o * 1024u + (k - 1024u)];
    }
    W1[d] = __float2bfloat16(v);
  }
}

// xbf[t][b][k] = bf16( t==0 ? 0 : x[b][t-1][k] )   (teacher forcing shift)
__global__ __launch_bounds__(256) void prep_x(const float* __restrict__ x,
                                              __hip_bfloat16* __restrict__ xbf) {
  const unsigned n = 512u * 64u * 256u;
  for (unsigned d = blockIdx.x * blockDim.x + threadIdx.x; d < n;
       d += blockDim.x * gridDim.x) {
    unsigned t = d >> 14;
    unsigned b = (d >> 8) & 63u;
    unsigned k = d & 255u;
    float v = (t == 0u) ? 0.f : x[((size_t)b * 512u + (t - 1u)) * 256u + k];
    xbf[d] = __float2bfloat16(v);
  }
}

// biases (gate-interleaved, bih+bhh combined) + h init (h=z); c lives in regs
__global__ __launch_bounds__(256) void prep_misc(
    const float* __restrict__ bih0, const float* __restrict__ bhh0,
    const float* __restrict__ bih1, const float* __restrict__ bhh1,
    const float* __restrict__ z, float* __restrict__ b0, float* __restrict__ b1,
    __hip_bfloat16* __restrict__ h0buf, __hip_bfloat16* __restrict__ h1buf) {
  for (int i = blockIdx.x * blockDim.x + threadIdx.x; i < 73728;
       i += blockDim.x * gridDim.x) {
    if (i < 4096) {
      int u = i >> 2, g = i & 3;
      b0[i] = bih0[g * 1024 + u] + bhh0[g * 1024 + u];
    } else if (i < 8192) {
      int r = i - 4096;
      int u = r >> 2, g = r & 3;
      b1[r] = bih1[g * 1024 + u] + bhh1[g * 1024 + u];
    } else {
      int j = i - 8192;  // 0..65535 -> parity-0 slot
      __hip_bfloat16 hb = __float2bfloat16(z[j]);
      h0buf[j] = hb;
      h1buf[j] = hb;
    }
  }
}

// ---------------- grid barrier (monotone, hierarchical 8x32) ----------------

__device__ __forceinline__ void bar_arrive(unsigned* __restrict__ root,
                                           unsigned* __restrict__ lvl,
                                           int phase, int tid) {
  __threadfence();       // release: make this thread's global writes visible
  __syncthreads();       // all block threads' writes ordered before arrive
  if (tid == 0) {
    unsigned old = __hip_atomic_fetch_add(lvl, 1u, __ATOMIC_RELEASE,
                                          __HIP_MEMORY_SCOPE_AGENT);
    if (old == (unsigned)phase * 32u + 31u)  // last of 32 in this group
      __hip_atomic_fetch_add(root, 1u, __ATOMIC_RELEASE,
                             __HIP_MEMORY_SCOPE_AGENT);
  }
}

__device__ __forceinline__ void bar_wait(unsigned* __restrict__ root, int phase,
                                         int tid) {
  if (tid == 0) {
    const unsigned tgt = (unsigned)(phase + 1) * 8u;
    while (__hip_atomic_load(root, __ATOMIC_RELAXED,
                             __HIP_MEMORY_SCOPE_AGENT) < tgt)
      __builtin_amdgcn_s_sleep(2);
  }
  __syncthreads();
  __threadfence();       // acquire: invalidate stale L1/L2 before h reads
}

// ---------------- projection helper (blocks 0..15) ----------------
// out[:, t_out, :] cols [pb*16, pb*16+16) = h1p @ Wlin^T + blin

__device__ __forceinline__ void do_proj(const __hip_bfloat16* __restrict__ h1p,
                                        const bf16x8* wp, float (*red)[16][68],
                                        const float* __restrict__ blin,
                                        float* __restrict__ out, int pb,
                                        int t_out, int tid, int w, int col,
                                        int kq) {
  f32x4 a0 = {0.f, 0.f, 0.f, 0.f}, a1 = a0, a2 = a0, a3 = a0;
  const __hip_bfloat16* ab = h1p + (w << 7) + (kq << 3);
#pragma unroll
  for (int c = 0; c < 4; ++c) {
    const __hip_bfloat16* p = ab + (c << 5);
    bf16x8 f0 = *(const bf16x8*)(p + ((size_t)col << 10));
    bf16x8 f1 = *(const bf16x8*)(p + ((size_t)(16 + col) << 10));
    bf16x8 f2 = *(const bf16x8*)(p + ((size_t)(32 + col) << 10));
    bf16x8 f3 = *(const bf16x8*)(p + ((size_t)(48 + col) << 10));
    a0 = __builtin_amdgcn_mfma_f32_16x16x32_bf16(f0, wp[c], a0, 0, 0, 0);
    a1 = __builtin_amdgcn_mfma_f32_16x16x32_bf16(f1, wp[c], a1, 0, 0, 0);
    a2 = __builtin_amdgcn_mfma_f32_16x16x32_bf16(f2, wp[c], a2, 0, 0, 0);
    a3 = __builtin_amdgcn_mfma_f32_16x16x32_bf16(f3, wp[c], a3, 0, 0, 0);
  }
  *(f32x4*)&red[w][col][(kq << 2)] = a0;
  *(f32x4*)&red[w][col][16 + (kq << 2)] = a1;
  *(f32x4*)&red[w][col][32 + (kq << 2)] = a2;
  *(f32x4*)&red[w][col][48 + (kq << 2)] = a3;
  __syncthreads();
#pragma unroll
  for (int i = 0; i < 2; ++i) {
    int idx = tid + (i << 9);
    int o_l = idx & 15, b = idx >> 4;
    float v = blin[(pb << 4) + o_l];
#pragma unroll
    for (int ww = 0; ww < 8; ++ww) v += red[ww][o_l][b];
    out[(((size_t)b << 9) + (size_t)t_out) * 256 + (pb << 4) + o_l] = v;
  }
}

// ---------------- persistent kernel ----------------

__global__ __launch_bounds__(512, 2) void k_persist(
    const __hip_bfloat16* __restrict__ xbf, const __hip_bfloat16* __restrict__ W0,
    const __hip_bfloat16* __restrict__ W1, const float* __restrict__ b0,
    const float* __restrict__ b1, const float* __restrict__ blin,
    __hip_bfloat16* __restrict__ h0buf, __hip_bfloat16* __restrict__ h1buf,
    float* __restrict__ out, unsigned* __restrict__ bar) {
  const int tid = threadIdx.x;
  const int lane = tid & 63;
  const int w = tid >> 6;          // wave id = K-split index (0..7)
  const int bid = blockIdx.x;
  const int cb = bid << 4;         // 16 gate-columns owned by this block
  const int col = lane & 15;
  const int kq = lane >> 4;
  const int n = cb + col;
  const bool isproj = (bid < 16);

  // ---- weights -> registers (persist across all 512 steps) ----
  bf16x8 wa[5], wb[8], wp[4];
  {
    const __hip_bfloat16* p = W0 + (size_t)n * 1280 + w * 160 + (kq << 3);
#pragma unroll
    for (int c = 0; c < 5; ++c) wa[c] = *(const bf16x8*)(p + (c << 5));
  }
  {
    const __hip_bfloat16* p = W1 + ((size_t)n << 11) + (w << 8) + (kq << 3);
#pragma unroll
    for (int c = 0; c < 8; ++c) wb[c] = *(const bf16x8*)(p + (c << 5));
  }
  if (isproj) {
    const __hip_bfloat16* p =
        W1 + ((size_t)(4096 + cb + col) << 11) + 1024 + (w << 7) + (kq << 3);
#pragma unroll
    for (int c = 0; c < 4; ++c) wp[c] = *(const bf16x8*)(p + (c << 5));
  } else {
#pragma unroll
    for (int c = 0; c < 4; ++c) wp[c] = bf16x8{0, 0, 0, 0, 0, 0, 0, 0};
  }

  // cell threads: tid<256 own (unit u_l of 4, batch bq); c-state in registers
  const int u_l = tid & 3, bq = tid >> 2;
  float bias0[4], bias1[4];
  if (tid < 256) {
#pragma unroll
    for (int g = 0; g < 4; ++g) {
      bias0[g] = b0[cb + (u_l << 2) + g];
      bias1[g] = b1[cb + (u_l << 2) + g];
    }
  }
  float c0v = 0.f, c1v = 0.f;

  __shared__ float red[8][16][68];  // K-partials; 68 keeps b128 16B-aligned

  unsigned* lvl = bar + 16 + ((bid & 7) << 6);  // 8 spread lvl-1 counters

  for (int t = 0; t < 512; ++t) {
    const __hip_bfloat16* h0prev = h0buf + ((size_t)(t & 1) << 16);
    const __hip_bfloat16* h0cur = h0buf + ((size_t)((t + 1) & 1) << 16);
    const __hip_bfloat16* h1prev = h1buf + ((size_t)(t & 1) << 16);

    // ======== phase A: gates0 = [x_t | h0prev] @ W0cat^T ========
    {
      f32x4 a0 = {0.f, 0.f, 0.f, 0.f}, a1 = a0, a2 = a0, a3 = a0;
#pragma unroll
      for (int c = 0; c < 5; ++c) {
        const int k0 = w * 160 + (c << 5);
        const __hip_bfloat16* ab;
        int rs;
        if (k0 < 256) {
          ab = xbf + ((size_t)t << 14) + k0 + (kq << 3);
          rs = 256;
        } else {
          ab = h0prev + (k0 - 256) + (kq << 3);
          rs = 1024;
        }
        bf16x8 f0 = *(const bf16x8*)(ab + (size_t)col * rs);
        bf16x8 f1 = *(const bf16x8*)(ab + (size_t)(16 + col) * rs);
        bf16x8 f2 = *(const bf16x8*)(ab + (size_t)(32 + col) * rs);
        bf16x8 f3 = *(const bf16x8*)(ab + (size_t)(48 + col) * rs);
        a0 = __builtin_amdgcn_mfma_f32_16x16x32_bf16(f0, wa[c], a0, 0, 0, 0);
        a1 = __builtin_amdgcn_mfma_f32_16x16x32_bf16(f1, wa[c], a1, 0, 0, 0);
        a2 = __builtin_amdgcn_mfma_f32_16x16x32_bf16(f2, wa[c], a2, 0, 0, 0);
        a3 = __builtin_amdgcn_mfma_f32_16x16x32_bf16(f3, wa[c], a3, 0, 0, 0);
      }
      *(f32x4*)&red[w][col][(kq << 2)] = a0;
      *(f32x4*)&red[w][col][16 + (kq << 2)] = a1;
      *(f32x4*)&red[w][col][32 + (kq << 2)] = a2;
      *(f32x4*)&red[w][col][48 + (kq << 2)] = a3;
    }
    __syncthreads();
    if (tid < 256) {  // 8-way K-reduce + LSTM cell 0
      float gg[4];
#pragma unroll
      for (int g = 0; g < 4; ++g) {
        float v = bias0[g];
#pragma unroll
        for (int ww = 0; ww < 8; ++ww) v += red[ww][(u_l << 2) + g][bq];
        gg[g] = v;
      }
      float cn = sigm(gg[1]) * c0v + sigm(gg[0]) * tanhf(gg[2]);
      c0v = cn;
      float hn = sigm(gg[3]) * tanhf(cn);
      h0buf[((size_t)((t + 1) & 1) << 16) + ((size_t)bq << 10) + (cb >> 2) +
            u_l] = __float2bfloat16(hn);
    }
    bar_arrive(bar, lvl, 2 * t, tid);  // publish h0[t]
    if (isproj && t > 0)               // overlap with barrier propagation
      do_proj(h1prev, wp, red, blin, out, bid, t - 1, tid, w, col, kq);
    bar_wait(bar, 2 * t, tid);

    // ======== phase B: gates1 = [h0cur | h1prev] @ W1^T ========
    {
      const __hip_bfloat16* ab =
          ((w < 4) ? h0cur : h1prev) + ((w & 3) << 8) + (kq << 3);
      f32x4 a0 = {0.f, 0.f, 0.f, 0.f}, a1 = a0, a2 = a0, a3 = a0;
#pragma unroll
      for (int c = 0; c < 8; ++c) {
        const __hip_bfloat16* p = ab + (c << 5);
        bf16x8 f0 = *(const bf16x8*)(p + ((size_t)col << 10));
        bf16x8 f1 = *(const bf16x8*)(p + ((size_t)(16 + col) << 10));
        bf16x8 f2 = *(const bf16x8*)(p + ((size_t)(32 + col) << 10));
        bf16x8 f3 = *(const bf16x8*)(p + ((size_t)(48 + col) << 10));
        a0 = __builtin_amdgcn_mfma_f32_16x16x32_bf16(f0, wb[c], a0, 0, 0, 0);
        a1 = __builtin_amdgcn_mfma_f32_16x16x32_bf16(f1, wb[c], a1, 0, 0, 0);
        a2 = __builtin_amdgcn_mfma_f32_16x16x32_bf16(f2, wb[c], a2, 0, 0, 0);
        a3 = __builtin_amdgcn_mfma_f32_16x16x32_bf16(f3, wb[c], a3, 0, 0, 0);
      }
      *(f32x4*)&red[w][col][(kq << 2)] = a0;
      *(f32x4*)&red[w][col][16 + (kq << 2)] = a1;
      *(f32x4*)&red[w][col][32 + (kq << 2)] = a2;
      *(f32x4*)&red[w][col][48 + (kq << 2)] = a3;
    }
    __syncthreads();
    if (tid < 256) {  // 8-way K-reduce + LSTM cell 1
      float gg[4];
#pragma unroll
      for (int g = 0; g < 4; ++g) {
        float v = bias1[g];
#pragma unroll
        for (int ww = 0; ww < 8; ++ww) v += red[ww][(u_l << 2) + g][bq];
        gg[g] = v;
      }
      float cn = sigm(gg[1]) * c1v + sigm(gg[0]) * tanhf(gg[2]);
      c1v = cn;
      float hn = sigm(gg[3]) * tanhf(cn);
      h1buf[((size_t)((t + 1) & 1) << 16) + ((size_t)bq << 10) + (cb >> 2) +
            u_l] = __float2bfloat16(hn);
    }
    bar_arrive(bar, lvl, 2 * t + 1, tid);  // publish h1[t]
    bar_wait(bar, 2 * t + 1, tid);
  }

  // final projection: out[:,511,:] from h1[511] (parity 0)
  if (isproj)
    do_proj(h1buf, wp, red, blin, out, bid, 511, tid, w, col, kq);
}

// ---------------- host launch ----------------

extern "C" void kernel_launch(void* const* d_in, const int* in_sizes, int n_in,
                              void* d_out, int out_size, void* d_ws, size_t ws_size,
                              hipStream_t stream) {
  const float* z = (const float*)d_in[0];
  const float* x = (const float*)d_in[1];
  const float* Wih0 = (const float*)d_in[2];
  const float* Whh0 = (const float*)d_in[3];
  const float* bih0 = (const float*)d_in[4];
  const float* bhh0 = (const float*)d_in[5];
  const float* Wih1 = (const float*)d_in[6];
  const float* Whh1 = (const float*)d_in[7];
  const float* bih1 = (const float*)d_in[8];
  const float* bhh1 = (const float*)d_in[9];
  const float* Wlin = (const float*)d_in[10];
  const float* blin = (const float*)d_in[11];
  float* out = (float*)d_out;

  char* ws = (char*)d_ws;
  __hip_bfloat16* W0 = (__hip_bfloat16*)(ws);                // 10,485,760 B
  __hip_bfloat16* W1 = (__hip_bfloat16*)(ws + 10485760);     // 17,825,792 B
  __hip_bfloat16* xbf = (__hip_bfloat16*)(ws + 28311552);    // 16,777,216 B
  float* b0 = (float*)(ws + 45088768);                       // 16,384 B
  float* b1 = (float*)(ws + 45105152);                       // 16,384 B
  __hip_bfloat16* h0buf = (__hip_bfloat16*)(ws + 45121536);  // 262,144 B
  __hip_bfloat16* h1buf = (__hip_bfloat16*)(ws + 45383680);  // 262,144 B
  unsigned* bar = (unsigned*)(ws + 45645824);                // 4,096 B

  hipMemsetAsync(bar, 0, 4096, stream);  // ws is re-poisoned every call
  prep_w0<<<4096, 256, 0, stream>>>(Wih0, Whh0, W0);
  prep_w1<<<4096, 256, 0, stream>>>(Wih1, Whh1, Wlin, W1);
  prep_x<<<4096, 256, 0, stream>>>(x, xbf);
  prep_misc<<<288, 256, 0, stream>>>(bih0, bhh0, bih1, bhh1, z, b0, b1, h0buf,
                                     h1buf);

  k_persist<<<256, 512, 0, stream>>>(xbf, W0, W1, b0, b1, blin, h0buf, h1buf,
                                     out, bar);
}

// Round 3
// 11486.450 us; speedup vs baseline: 7.6576x; 7.6576x over previous
//
#include <hip/hip_runtime.h>
#include <hip/hip_bf16.h>
#include <math.h>

// LSTM decoder: B=64, T=512, IN=256, OUT=256, H=1024, 2 layers + linear head.
// Round 3: persistent kernel (256 blocks x 512 threads), weights in VGPRs,
// cell state in registers. h0/h1 exchanged through the LLC using VOLATILE
// (sc0 sc1 write/read-through) accesses so NO cache-maintenance fences are
// needed; grid barrier is relaxed-atomic only (R2's __threadfence -> 83us/
// barrier via buffer_wbl2/buffer_inv was the regression cause).

typedef __attribute__((ext_vector_type(8))) short bf16x8;   // 8 x bf16
typedef __attribute__((ext_vector_type(4))) float f32x4;

__device__ __forceinline__ float sigm(float v) { return 1.f / (1.f + expf(-v)); }

// volatile (cache-bypassing) 16B load / 2B store for h exchange
__device__ __forceinline__ bf16x8 vload16(const __hip_bfloat16* p) {
  return *(const volatile bf16x8*)p;
}
__device__ __forceinline__ void vstore_bf16(__hip_bfloat16* p, float v) {
  __hip_bfloat16 hb = __float2bfloat16(v);
  unsigned short us;
  __builtin_memcpy(&us, &hb, 2);
  *(volatile unsigned short*)p = us;
}

// ---------------- prep kernels (one-time per launch) ----------------

// W0cat[u*4+g][k] : k<256 -> Wih0[g*1024+u][k], else Whh0[g*1024+u][k-256]
__global__ __launch_bounds__(256) void prep_w0(const float* __restrict__ Wih0,
                                               const float* __restrict__ Whh0,
                                               __hip_bfloat16* __restrict__ W0) {
  const unsigned n = 4096u * 1280u;
  for (unsigned d = blockIdx.x * blockDim.x + threadIdx.x; d < n;
       d += blockDim.x * gridDim.x) {
    unsigned r = d / 1280u;
    unsigned k = d - r * 1280u;
    unsigned u = r >> 2, g = r & 3u;
    unsigned srow = g * 1024u + u;
    float v = (k < 256u) ? Wih0[(size_t)srow * 256u + k]
                         : Whh0[(size_t)srow * 1024u + (k - 256u)];
    W0[d] = __float2bfloat16(v);
  }
}

// W1ext[4352][2048]: rows<4096 reordered LSTM1 weights [Wih1|Whh1];
// rows 4096+o: [zeros(1024) | Wlin[o]]
__global__ __launch_bounds__(256) void prep_w1(const float* __restrict__ Wih1,
                                               const float* __restrict__ Whh1,
                                               const float* __restrict__ Wlin,
                                               __hip_bfloat16* __restrict__ W1) {
  const unsigned n = 4352u * 2048u;
  for (unsigned d = blockIdx.x * blockDim.x + threadIdx.x; d < n;
       d += blockDim.x * gridDim.x) {
    unsigned r = d >> 11;
    unsigned k = d & 2047u;
    float v;
    if (r < 4096u) {
      unsigned u = r >> 2, g = r & 3u;
      unsigned srow = g * 1024u + u;
      v = (k < 1024u) ? Wih1[(size_t)srow * 1024u + k]
                      : Whh1[(size_t)srow * 1024u + (k - 1024u)];
    } else {
      unsigned o = r - 4096u;
      v = (k < 1024u) ? 0.f : Wlin[(size_t)o * 1024u + (k - 1024u)];
    }
    W1[d] = __float2bfloat16(v);
  }
}

// xbf[t][b][k] = bf16( t==0 ? 0 : x[b][t-1][k] )   (teacher forcing shift)
__global__ __launch_bounds__(256) void prep_x(const float* __restrict__ x,
                                              __hip_bfloat16* __restrict__ xbf) {
  const unsigned n = 512u * 64u * 256u;
  for (unsigned d = blockIdx.x * blockDim.x + threadIdx.x; d < n;
       d += blockDim.x * gridDim.x) {
    unsigned t = d >> 14;
    unsigned b = (d >> 8) & 63u;
    unsigned k = d & 255u;
    float v = (t == 0u) ? 0.f : x[((size_t)b * 512u + (t - 1u)) * 256u + k];
    xbf[d] = __float2bfloat16(v);
  }
}

// biases (gate-interleaved, bih+bhh combined) + h init (h=z); c lives in regs
__global__ __launch_bounds__(256) void prep_misc(
    const float* __restrict__ bih0, const float* __restrict__ bhh0,
    const float* __restrict__ bih1, const float* __restrict__ bhh1,
    const float* __restrict__ z, float* __restrict__ b0, float* __restrict__ b1,
    __hip_bfloat16* __restrict__ h0buf, __hip_bfloat16* __restrict__ h1buf) {
  for (int i = blockIdx.x * blockDim.x + threadIdx.x; i < 73728;
       i += blockDim.x * gridDim.x) {
    if (i < 4096) {
      int u = i >> 2, g = i & 3;
      b0[i] = bih0[g * 1024 + u] + bhh0[g * 1024 + u];
    } else if (i < 8192) {
      int r = i - 4096;
      int u = r >> 2, g = r & 3;
      b1[r] = bih1[g * 1024 + u] + bhh1[g * 1024 + u];
    } else {
      int j = i - 8192;  // 0..65535 -> parity-0 slot
      float zv = z[j];
      vstore_bf16(h0buf + j, zv);   // write-through: k_persist reads volatile
      vstore_bf16(h1buf + j, zv);
    }
  }
}

// ------------- grid barrier: relaxed atomics ONLY, no cache ops -------------
// Safe because ALL cross-block data (h0/h1) moves via volatile (sc0 sc1)
// accesses that hit the LLC coherence point directly; __syncthreads()'s
// implicit s_waitcnt vmcnt(0) drains the write-through stores before arrive.

__device__ __forceinline__ void bar_arrive(unsigned* __restrict__ root,
                                           unsigned* __restrict__ lvl,
                                           int phase, int tid) {
  __builtin_amdgcn_s_waitcnt(0);   // belt: drain vmcnt before signaling
  __syncthreads();                 // (also drains; orders all waves' stores)
  if (tid == 0) {
    unsigned old = __hip_atomic_fetch_add(lvl, 1u, __ATOMIC_RELAXED,
                                          __HIP_MEMORY_SCOPE_AGENT);
    if (old == (unsigned)phase * 32u + 31u)  // last of 32 in this group
      __hip_atomic_fetch_add(root, 1u, __ATOMIC_RELAXED,
                             __HIP_MEMORY_SCOPE_AGENT);
  }
}

__device__ __forceinline__ void bar_wait(unsigned* __restrict__ root, int phase,
                                         int tid) {
  if (tid == 0) {
    const unsigned tgt = (unsigned)(phase + 1) * 8u;
    while (__hip_atomic_load(root, __ATOMIC_RELAXED,
                             __HIP_MEMORY_SCOPE_AGENT) < tgt)
      __builtin_amdgcn_s_sleep(2);
  }
  __syncthreads();                 // readers use volatile loads -> no inv
}

// ---------------- projection helper (blocks 0..15) ----------------
// out[:, t_out, :] cols [pb*16, pb*16+16) = h1p @ Wlin^T + blin

__device__ __forceinline__ void do_proj(const __hip_bfloat16* __restrict__ h1p,
                                        const bf16x8* wp, float (*red)[16][68],
                                        const float* __restrict__ blin,
                                        float* __restrict__ out, int pb,
                                        int t_out, int tid, int w, int col,
                                        int kq) {
  f32x4 a0 = {0.f, 0.f, 0.f, 0.f}, a1 = a0, a2 = a0, a3 = a0;
  const __hip_bfloat16* ab = h1p + (w << 7) + (kq << 3);
#pragma unroll
  for (int c = 0; c < 4; ++c) {
    const __hip_bfloat16* p = ab + (c << 5);
    bf16x8 f0 = vload16(p + ((size_t)col << 10));
    bf16x8 f1 = vload16(p + ((size_t)(16 + col) << 10));
    bf16x8 f2 = vload16(p + ((size_t)(32 + col) << 10));
    bf16x8 f3 = vload16(p + ((size_t)(48 + col) << 10));
    a0 = __builtin_amdgcn_mfma_f32_16x16x32_bf16(f0, wp[c], a0, 0, 0, 0);
    a1 = __builtin_amdgcn_mfma_f32_16x16x32_bf16(f1, wp[c], a1, 0, 0, 0);
    a2 = __builtin_amdgcn_mfma_f32_16x16x32_bf16(f2, wp[c], a2, 0, 0, 0);
    a3 = __builtin_amdgcn_mfma_f32_16x16x32_bf16(f3, wp[c], a3, 0, 0, 0);
  }
  *(f32x4*)&red[w][col][(kq << 2)] = a0;
  *(f32x4*)&red[w][col][16 + (kq << 2)] = a1;
  *(f32x4*)&red[w][col][32 + (kq << 2)] = a2;
  *(f32x4*)&red[w][col][48 + (kq << 2)] = a3;
  __syncthreads();
#pragma unroll
  for (int i = 0; i < 2; ++i) {
    int idx = tid + (i << 9);
    int o_l = idx & 15, b = idx >> 4;
    float v = blin[(pb << 4) + o_l];
#pragma unroll
    for (int ww = 0; ww < 8; ++ww) v += red[ww][o_l][b];
    out[(((size_t)b << 9) + (size_t)t_out) * 256 + (pb << 4) + o_l] = v;
  }
}

// ---------------- persistent kernel ----------------

__global__ __launch_bounds__(512) void k_persist(
    const __hip_bfloat16* __restrict__ xbf, const __hip_bfloat16* __restrict__ W0,
    const __hip_bfloat16* __restrict__ W1, const float* __restrict__ b0,
    const float* __restrict__ b1, const float* __restrict__ blin,
    __hip_bfloat16* __restrict__ h0buf, __hip_bfloat16* __restrict__ h1buf,
    float* __restrict__ out, unsigned* __restrict__ bar) {
  const int tid = threadIdx.x;
  const int lane = tid & 63;
  const int w = tid >> 6;          // wave id = K-split index (0..7)
  const int bid = blockIdx.x;
  const int cb = bid << 4;         // 16 gate-columns owned by this block
  const int col = lane & 15;
  const int kq = lane >> 4;
  const int n = cb + col;
  const bool isproj = (bid < 16);

  // ---- weights -> registers (persist across all 512 steps) ----
  bf16x8 wa[5], wb[8], wp[4];
  {
    const __hip_bfloat16* p = W0 + (size_t)n * 1280 + w * 160 + (kq << 3);
#pragma unroll
    for (int c = 0; c < 5; ++c) wa[c] = *(const bf16x8*)(p + (c << 5));
  }
  {
    const __hip_bfloat16* p = W1 + ((size_t)n << 11) + (w << 8) + (kq << 3);
#pragma unroll
    for (int c = 0; c < 8; ++c) wb[c] = *(const bf16x8*)(p + (c << 5));
  }
  if (isproj) {
    const __hip_bfloat16* p =
        W1 + ((size_t)(4096 + cb + col) << 11) + 1024 + (w << 7) + (kq << 3);
#pragma unroll
    for (int c = 0; c < 4; ++c) wp[c] = *(const bf16x8*)(p + (c << 5));
  } else {
#pragma unroll
    for (int c = 0; c < 4; ++c) wp[c] = bf16x8{0, 0, 0, 0, 0, 0, 0, 0};
  }

  // cell threads: tid<256 own (unit u_l of 4, batch bq); c-state in registers
  const int u_l = tid & 3, bq = tid >> 2;
  float bias0[4], bias1[4];
  if (tid < 256) {
#pragma unroll
    for (int g = 0; g < 4; ++g) {
      bias0[g] = b0[cb + (u_l << 2) + g];
      bias1[g] = b1[cb + (u_l << 2) + g];
    }
  }
  float c0v = 0.f, c1v = 0.f;

  __shared__ float red[8][16][68];  // K-partials; 68 keeps b128 16B-aligned

  unsigned* lvl = bar + 16 + ((bid & 7) << 6);  // 8 spread lvl-1 counters

  for (int t = 0; t < 512; ++t) {
    const __hip_bfloat16* h0prev = h0buf + ((size_t)(t & 1) << 16);
    const __hip_bfloat16* h0cur = h0buf + ((size_t)((t + 1) & 1) << 16);
    const __hip_bfloat16* h1prev = h1buf + ((size_t)(t & 1) << 16);

    // ======== phase A: gates0 = [x_t | h0prev] @ W0cat^T ========
    {
      f32x4 a0 = {0.f, 0.f, 0.f, 0.f}, a1 = a0, a2 = a0, a3 = a0;
#pragma unroll
      for (int c = 0; c < 5; ++c) {
        const int k0 = w * 160 + (c << 5);
        bf16x8 f0, f1, f2, f3;
        if (k0 < 256) {  // x part: cached (written once by prep)
          const __hip_bfloat16* ab = xbf + ((size_t)t << 14) + k0 + (kq << 3);
          f0 = *(const bf16x8*)(ab + ((size_t)col << 8));
          f1 = *(const bf16x8*)(ab + ((size_t)(16 + col) << 8));
          f2 = *(const bf16x8*)(ab + ((size_t)(32 + col) << 8));
          f3 = *(const bf16x8*)(ab + ((size_t)(48 + col) << 8));
        } else {         // h part: volatile (LLC-coherent)
          const __hip_bfloat16* ab = h0prev + (k0 - 256) + (kq << 3);
          f0 = vload16(ab + ((size_t)col << 10));
          f1 = vload16(ab + ((size_t)(16 + col) << 10));
          f2 = vload16(ab + ((size_t)(32 + col) << 10));
          f3 = vload16(ab + ((size_t)(48 + col) << 10));
        }
        a0 = __builtin_amdgcn_mfma_f32_16x16x32_bf16(f0, wa[c], a0, 0, 0, 0);
        a1 = __builtin_amdgcn_mfma_f32_16x16x32_bf16(f1, wa[c], a1, 0, 0, 0);
        a2 = __builtin_amdgcn_mfma_f32_16x16x32_bf16(f2, wa[c], a2, 0, 0, 0);
        a3 = __builtin_amdgcn_mfma_f32_16x16x32_bf16(f3, wa[c], a3, 0, 0, 0);
      }
      *(f32x4*)&red[w][col][(kq << 2)] = a0;
      *(f32x4*)&red[w][col][16 + (kq << 2)] = a1;
      *(f32x4*)&red[w][col][32 + (kq << 2)] = a2;
      *(f32x4*)&red[w][col][48 + (kq << 2)] = a3;
    }
    __syncthreads();
    if (tid < 256) {  // 8-way K-reduce + LSTM cell 0
      float gg[4];
#pragma unroll
      for (int g = 0; g < 4; ++g) {
        float v = bias0[g];
#pragma unroll
        for (int ww = 0; ww < 8; ++ww) v += red[ww][(u_l << 2) + g][bq];
        gg[g] = v;
      }
      float cn = sigm(gg[1]) * c0v + sigm(gg[0]) * tanhf(gg[2]);
      c0v = cn;
      float hn = sigm(gg[3]) * tanhf(cn);
      vstore_bf16(h0buf + ((size_t)((t + 1) & 1) << 16) + ((size_t)bq << 10) +
                      (cb >> 2) + u_l,
                  hn);
    }
    bar_arrive(bar, lvl, 2 * t, tid);  // publish h0[t]
    if (isproj && t > 0)               // overlap with barrier propagation
      do_proj(h1prev, wp, red, blin, out, bid, t - 1, tid, w, col, kq);
    bar_wait(bar, 2 * t, tid);

    // ======== phase B: gates1 = [h0cur | h1prev] @ W1^T ========
    {
      const __hip_bfloat16* ab =
          ((w < 4) ? h0cur : h1prev) + ((w & 3) << 8) + (kq << 3);
      f32x4 a0 = {0.f, 0.f, 0.f, 0.f}, a1 = a0, a2 = a0, a3 = a0;
#pragma unroll
      for (int c = 0; c < 8; ++c) {
        const __hip_bfloat16* p = ab + (c << 5);
        bf16x8 f0 = vload16(p + ((size_t)col << 10));
        bf16x8 f1 = vload16(p + ((size_t)(16 + col) << 10));
        bf16x8 f2 = vload16(p + ((size_t)(32 + col) << 10));
        bf16x8 f3 = vload16(p + ((size_t)(48 + col) << 10));
        a0 = __builtin_amdgcn_mfma_f32_16x16x32_bf16(f0, wb[c], a0, 0, 0, 0);
        a1 = __builtin_amdgcn_mfma_f32_16x16x32_bf16(f1, wb[c], a1, 0, 0, 0);
        a2 = __builtin_amdgcn_mfma_f32_16x16x32_bf16(f2, wb[c], a2, 0, 0, 0);
        a3 = __builtin_amdgcn_mfma_f32_16x16x32_bf16(f3, wb[c], a3, 0, 0, 0);
      }
      *(f32x4*)&red[w][col][(kq << 2)] = a0;
      *(f32x4*)&red[w][col][16 + (kq << 2)] = a1;
      *(f32x4*)&red[w][col][32 + (kq << 2)] = a2;
      *(f32x4*)&red[w][col][48 + (kq << 2)] = a3;
    }
    __syncthreads();
    if (tid < 256) {  // 8-way K-reduce + LSTM cell 1
      float gg[4];
#pragma unroll
      for (int g = 0; g < 4; ++g) {
        float v = bias1[g];
#pragma unroll
        for (int ww = 0; ww < 8; ++ww) v += red[ww][(u_l << 2) + g][bq];
        gg[g] = v;
      }
      float cn = sigm(gg[1]) * c1v + sigm(gg[0]) * tanhf(gg[2]);
      c1v = cn;
      float hn = sigm(gg[3]) * tanhf(cn);
      vstore_bf16(h1buf + ((size_t)((t + 1) & 1) << 16) + ((size_t)bq << 10) +
                      (cb >> 2) + u_l,
                  hn);
    }
    bar_arrive(bar, lvl, 2 * t + 1, tid);  // publish h1[t]
    bar_wait(bar, 2 * t + 1, tid);
  }

  // final projection: out[:,511,:] from h1[511] (parity 0)
  if (isproj)
    do_proj(h1buf, wp, red, blin, out, bid, 511, tid, w, col, kq);
}

// ---------------- host launch ----------------

extern "C" void kernel_launch(void* const* d_in, const int* in_sizes, int n_in,
                              void* d_out, int out_size, void* d_ws, size_t ws_size,
                              hipStream_t stream) {
  const float* z = (const float*)d_in[0];
  const float* x = (const float*)d_in[1];
  const float* Wih0 = (const float*)d_in[2];
  const float* Whh0 = (const float*)d_in[3];
  const float* bih0 = (const float*)d_in[4];
  const float* bhh0 = (const float*)d_in[5];
  const float* Wih1 = (const float*)d_in[6];
  const float* Whh1 = (const float*)d_in[7];
  const float* bih1 = (const float*)d_in[8];
  const float* bhh1 = (const float*)d_in[9];
  const float* Wlin = (const float*)d_in[10];
  const float* blin = (const float*)d_in[11];
  float* out = (float*)d_out;

  char* ws = (char*)d_ws;
  __hip_bfloat16* W0 = (__hip_bfloat16*)(ws);                // 10,485,760 B
  __hip_bfloat16* W1 = (__hip_bfloat16*)(ws + 10485760);     // 17,825,792 B
  __hip_bfloat16* xbf = (__hip_bfloat16*)(ws + 28311552);    // 16,777,216 B
  float* b0 = (float*)(ws + 45088768);                       // 16,384 B
  float* b1 = (float*)(ws + 45105152);                       // 16,384 B
  __hip_bfloat16* h0buf = (__hip_bfloat16*)(ws + 45121536);  // 262,144 B
  __hip_bfloat16* h1buf = (__hip_bfloat16*)(ws + 45383680);  // 262,144 B
  unsigned* bar = (unsigned*)(ws + 45645824);                // 4,096 B

  hipMemsetAsync(bar, 0, 4096, stream);  // ws is re-poisoned every call
  prep_w0<<<4096, 256, 0, stream>>>(Wih0, Whh0, W0);
  prep_w1<<<4096, 256, 0, stream>>>(Wih1, Whh1, Wlin, W1);
  prep_x<<<4096, 256, 0, stream>>>(x, xbf);
  prep_misc<<<288, 256, 0, stream>>>(bih0, bhh0, bih1, bhh1, z, b0, b1, h0buf,
                                     h1buf);

  k_persist<<<256, 512, 0, stream>>>(xbf, W0, W1, b0, b1, blin, h0buf, h1buf,
                                     out, bar);
}

// Round 4
// 10307.993 us; speedup vs baseline: 8.5330x; 1.1143x over previous
//
#include <hip/hip_runtime.h>
#include <hip/hip_bf16.h>
#include <math.h>

// LSTM decoder: B=64, T=512, IN=256, OUT=256, H=1024, 2 layers + linear head.
// Round 4: persistent kernel (256 blocks x 512 threads), weights in VGPRs,
// cell state in registers. Changes vs R3:
//  - h loads are CACHED (L1/L2); coherence via one acquire-only agent fence
//    (buffer_inv, no writeback) per barrier. h stores remain write-through
//    volatile (sc0 sc1) so data reaches the LLC coherence point pre-arrive.
//  - ONE grid barrier per step (was 2): schedule A_t; bar(t); B_t; A_{t+1}.
//    bar(t) publishes h0[t] (A_t) and h1[t-1] (B_{t-1}). h1 triple-buffered
//    to keep all WAR pairs barrier-separated.
//  - Projection of h1[t-2] runs in the barrier stall window (arrive..wait)
//    on blocks 0..15; operand is L1-resident (read by B_{t-1}). Tail t=510,
//    511 projected after a final barrier.

typedef __attribute__((ext_vector_type(8))) short bf16x8;   // 8 x bf16
typedef __attribute__((ext_vector_type(4))) float f32x4;

__device__ __forceinline__ float sigm(float v) { return 1.f / (1.f + expf(-v)); }

// write-through (sc0 sc1) 2B store for h publication
__device__ __forceinline__ void vstore_bf16(__hip_bfloat16* p, float v) {
  __hip_bfloat16 hb = __float2bfloat16(v);
  unsigned short us;
  __builtin_memcpy(&us, &hb, 2);
  *(volatile unsigned short*)p = us;
}

// ---------------- prep kernels (one-time per launch) ----------------

// W0cat[u*4+g][k] : k<256 -> Wih0[g*1024+u][k], else Whh0[g*1024+u][k-256]
__global__ __launch_bounds__(256) void prep_w0(const float* __restrict__ Wih0,
                                               const float* __restrict__ Whh0,
                                               __hip_bfloat16* __restrict__ W0) {
  const unsigned n = 4096u * 1280u;
  for (unsigned d = blockIdx.x * blockDim.x + threadIdx.x; d < n;
       d += blockDim.x * gridDim.x) {
    unsigned r = d / 1280u;
    unsigned k = d - r * 1280u;
    unsigned u = r >> 2, g = r & 3u;
    unsigned srow = g * 1024u + u;
    float v = (k < 256u) ? Wih0[(size_t)srow * 256u + k]
                         : Whh0[(size_t)srow * 1024u + (k - 256u)];
    W0[d] = __float2bfloat16(v);
  }
}

// W1ext[4352][2048]: rows<4096 reordered LSTM1 weights [Wih1|Whh1];
// rows 4096+o: [zeros(1024) | Wlin[o]]
__global__ __launch_bounds__(256) void prep_w1(const float* __restrict__ Wih1,
                                               const float* __restrict__ Whh1,
                                               const float* __restrict__ Wlin,
                                               __hip_bfloat16* __restrict__ W1) {
  const unsigned n = 4352u * 2048u;
  for (unsigned d = blockIdx.x * blockDim.x + threadIdx.x; d < n;
       d += blockDim.x * gridDim.x) {
    unsigned r = d >> 11;
    unsigned k = d & 2047u;
    float v;
    if (r < 4096u) {
      unsigned u = r >> 2, g = r & 3u;
      unsigned srow = g * 1024u + u;
      v = (k < 1024u) ? Wih1[(size_t)srow * 1024u + k]
                      : Whh1[(size_t)srow * 1024u + (k - 1024u)];
    } else {
      unsigned o = r - 4096u;
      v = (k < 1024u) ? 0.f : Wlin[(size_t)o * 1024u + (k - 1024u)];
    }
    W1[d] = __float2bfloat16(v);
  }
}

// xbf[t][b][k] = bf16( t==0 ? 0 : x[b][t-1][k] )   (teacher forcing shift)
__global__ __launch_bounds__(256) void prep_x(const float* __restrict__ x,
                                              __hip_bfloat16* __restrict__ xbf) {
  const unsigned n = 512u * 64u * 256u;
  for (unsigned d = blockIdx.x * blockDim.x + threadIdx.x; d < n;
       d += blockDim.x * gridDim.x) {
    unsigned t = d >> 14;
    unsigned b = (d >> 8) & 63u;
    unsigned k = d & 255u;
    float v = (t == 0u) ? 0.f : x[((size_t)b * 512u + (t - 1u)) * 256u + k];
    xbf[d] = __float2bfloat16(v);
  }
}

// biases (gate-interleaved, bih+bhh combined) + h init: h0[-1] -> slot 0,
// h1[-1] -> slot 2 (h1 is triple-buffered, B_0 reads slot (0+2)%3 = 2)
__global__ __launch_bounds__(256) void prep_misc(
    const float* __restrict__ bih0, const float* __restrict__ bhh0,
    const float* __restrict__ bih1, const float* __restrict__ bhh1,
    const float* __restrict__ z, float* __restrict__ b0, float* __restrict__ b1,
    __hip_bfloat16* __restrict__ h0buf, __hip_bfloat16* __restrict__ h1buf) {
  for (int i = blockIdx.x * blockDim.x + threadIdx.x; i < 73728;
       i += blockDim.x * gridDim.x) {
    if (i < 4096) {
      int u = i >> 2, g = i & 3;
      b0[i] = bih0[g * 1024 + u] + bhh0[g * 1024 + u];
    } else if (i < 8192) {
      int r = i - 4096;
      int u = r >> 2, g = r & 3;
      b1[r] = bih1[g * 1024 + u] + bhh1[g * 1024 + u];
    } else {
      int j = i - 8192;  // 0..65535
      float zv = z[j];
      vstore_bf16(h0buf + j, zv);                       // h0 slot 0
      vstore_bf16(h1buf + 2 * 65536 + j, zv);           // h1 slot 2
    }
  }
}

// ------------- grid barrier: relaxed atomics + acquire-only inv -------------

__device__ __forceinline__ void bar_arrive(unsigned* __restrict__ root,
                                           unsigned* __restrict__ lvl,
                                           int phase, int tid) {
  __builtin_amdgcn_s_waitcnt(0);   // drain write-through h stores
  __syncthreads();                 // order all waves' stores before signal
  if (tid == 0) {
    unsigned old = __hip_atomic_fetch_add(lvl, 1u, __ATOMIC_RELAXED,
                                          __HIP_MEMORY_SCOPE_AGENT);
    if (old == (unsigned)phase * 32u + 31u)  // last of 32 in this group
      __hip_atomic_fetch_add(root, 1u, __ATOMIC_RELAXED,
                             __HIP_MEMORY_SCOPE_AGENT);
  }
}

__device__ __forceinline__ void bar_wait(unsigned* __restrict__ root, int phase,
                                         int tid) {
  if (tid == 0) {
    const unsigned tgt = (unsigned)(phase + 1) * 8u;
    while (__hip_atomic_load(root, __ATOMIC_RELAXED,
                             __HIP_MEMORY_SCOPE_AGENT) < tgt)
      __builtin_amdgcn_s_sleep(2);
    // acquire: s_waitcnt + buffer_inv (L1+L2 invalidate, NO writeback).
    // Per-CU physical cache op -> one wave suffices for the whole block.
    __builtin_amdgcn_fence(__ATOMIC_ACQUIRE, "agent");
  }
  __syncthreads();
}

// ---------------- projection helper (blocks 0..15) ----------------
// out[:, t_out, :] cols [pb*16, pb*16+16) = h1p @ Wlin^T + blin

__device__ __forceinline__ void do_proj(const __hip_bfloat16* __restrict__ h1p,
                                        const bf16x8* wp, float (*red)[16][68],
                                        const float* __restrict__ blin,
                                        float* __restrict__ out, int pb,
                                        int t_out, int tid, int w, int col,
                                        int kq) {
  f32x4 a0 = {0.f, 0.f, 0.f, 0.f}, a1 = a0, a2 = a0, a3 = a0;
  const __hip_bfloat16* ab = h1p + (w << 7) + (kq << 3);
#pragma unroll
  for (int c = 0; c < 4; ++c) {
    const __hip_bfloat16* p = ab + (c << 5);
    bf16x8 f0 = *(const bf16x8*)(p + ((size_t)col << 10));
    bf16x8 f1 = *(const bf16x8*)(p + ((size_t)(16 + col) << 10));
    bf16x8 f2 = *(const bf16x8*)(p + ((size_t)(32 + col) << 10));
    bf16x8 f3 = *(const bf16x8*)(p + ((size_t)(48 + col) << 10));
    a0 = __builtin_amdgcn_mfma_f32_16x16x32_bf16(f0, wp[c], a0, 0, 0, 0);
    a1 = __builtin_amdgcn_mfma_f32_16x16x32_bf16(f1, wp[c], a1, 0, 0, 0);
    a2 = __builtin_amdgcn_mfma_f32_16x16x32_bf16(f2, wp[c], a2, 0, 0, 0);
    a3 = __builtin_amdgcn_mfma_f32_16x16x32_bf16(f3, wp[c], a3, 0, 0, 0);
  }
  *(f32x4*)&red[w][col][(kq << 2)] = a0;
  *(f32x4*)&red[w][col][16 + (kq << 2)] = a1;
  *(f32x4*)&red[w][col][32 + (kq << 2)] = a2;
  *(f32x4*)&red[w][col][48 + (kq << 2)] = a3;
  __syncthreads();
#pragma unroll
  for (int i = 0; i < 2; ++i) {
    int idx = tid + (i << 9);
    int o_l = idx & 15, b = idx >> 4;
    float v = blin[(pb << 4) + o_l];
#pragma unroll
    for (int ww = 0; ww < 8; ++ww) v += red[ww][o_l][b];
    out[(((size_t)b << 9) + (size_t)t_out) * 256 + (pb << 4) + o_l] = v;
  }
  __syncthreads();  // red reused right after (phase B)
}

// ---------------- persistent kernel ----------------

__global__ __launch_bounds__(512) void k_persist(
    const __hip_bfloat16* __restrict__ xbf, const __hip_bfloat16* __restrict__ W0,
    const __hip_bfloat16* __restrict__ W1, const float* __restrict__ b0,
    const float* __restrict__ b1, const float* __restrict__ blin,
    __hip_bfloat16* __restrict__ h0buf, __hip_bfloat16* __restrict__ h1buf,
    float* __restrict__ out, unsigned* __restrict__ bar) {
  const int tid = threadIdx.x;
  const int lane = tid & 63;
  const int w = tid >> 6;          // wave id = K-split index (0..7)
  const int bid = blockIdx.x;
  const int cb = bid << 4;         // 16 gate-columns owned by this block
  const int col = lane & 15;
  const int kq = lane >> 4;
  const int n = cb + col;
  const bool isproj = (bid < 16);

  // ---- weights -> registers (persist across all 512 steps) ----
  bf16x8 wa[5], wb[8], wp[4];
  {
    const __hip_bfloat16* p = W0 + (size_t)n * 1280 + w * 160 + (kq << 3);
#pragma unroll
    for (int c = 0; c < 5; ++c) wa[c] = *(const bf16x8*)(p + (c << 5));
  }
  {
    const __hip_bfloat16* p = W1 + ((size_t)n << 11) + (w << 8) + (kq << 3);
#pragma unroll
    for (int c = 0; c < 8; ++c) wb[c] = *(const bf16x8*)(p + (c << 5));
  }
  if (isproj) {
    const __hip_bfloat16* p =
        W1 + ((size_t)(4096 + cb + col) << 11) + 1024 + (w << 7) + (kq << 3);
#pragma unroll
    for (int c = 0; c < 4; ++c) wp[c] = *(const bf16x8*)(p + (c << 5));
  } else {
#pragma unroll
    for (int c = 0; c < 4; ++c) wp[c] = bf16x8{0, 0, 0, 0, 0, 0, 0, 0};
  }

  // cell threads: tid<256 own (unit u_l of 4, batch bq); c-state in registers
  const int u_l = tid & 3, bq = tid >> 2;
  float bias0[4], bias1[4];
  if (tid < 256) {
#pragma unroll
    for (int g = 0; g < 4; ++g) {
      bias0[g] = b0[cb + (u_l << 2) + g];
      bias1[g] = b1[cb + (u_l << 2) + g];
    }
  }
  float c0v = 0.f, c1v = 0.f;

  __shared__ float red[8][16][68];  // K-partials; 68 keeps b128 16B-aligned

  unsigned* lvl = bar + 16 + ((bid & 7) << 6);  // 8 spread lvl-1 counters

  for (int t = 0; t < 512; ++t) {
    const __hip_bfloat16* h0prev = h0buf + ((size_t)(t & 1) << 16);
    const __hip_bfloat16* h0cur = h0buf + ((size_t)((t + 1) & 1) << 16);
    const __hip_bfloat16* h1prev = h1buf + ((size_t)((t + 2) % 3) << 16);
    const __hip_bfloat16* h1proj = h1buf + ((size_t)((t + 1) % 3) << 16);

    // ======== phase A: gates0 = [x_t | h0prev] @ W0cat^T ========
    {
      f32x4 a0 = {0.f, 0.f, 0.f, 0.f}, a1 = a0, a2 = a0, a3 = a0;
#pragma unroll
      for (int c = 0; c < 5; ++c) {
        const int k0 = w * 160 + (c << 5);
        const __hip_bfloat16* ab;
        size_t rs;
        if (k0 < 256) {  // x part
          ab = xbf + ((size_t)t << 14) + k0 + (kq << 3);
          rs = 256;
        } else {         // h part (cached; fresh since last buffer_inv)
          ab = h0prev + (k0 - 256) + (kq << 3);
          rs = 1024;
        }
        bf16x8 f0 = *(const bf16x8*)(ab + (size_t)col * rs);
        bf16x8 f1 = *(const bf16x8*)(ab + (size_t)(16 + col) * rs);
        bf16x8 f2 = *(const bf16x8*)(ab + (size_t)(32 + col) * rs);
        bf16x8 f3 = *(const bf16x8*)(ab + (size_t)(48 + col) * rs);
        a0 = __builtin_amdgcn_mfma_f32_16x16x32_bf16(f0, wa[c], a0, 0, 0, 0);
        a1 = __builtin_amdgcn_mfma_f32_16x16x32_bf16(f1, wa[c], a1, 0, 0, 0);
        a2 = __builtin_amdgcn_mfma_f32_16x16x32_bf16(f2, wa[c], a2, 0, 0, 0);
        a3 = __builtin_amdgcn_mfma_f32_16x16x32_bf16(f3, wa[c], a3, 0, 0, 0);
      }
      *(f32x4*)&red[w][col][(kq << 2)] = a0;
      *(f32x4*)&red[w][col][16 + (kq << 2)] = a1;
      *(f32x4*)&red[w][col][32 + (kq << 2)] = a2;
      *(f32x4*)&red[w][col][48 + (kq << 2)] = a3;
    }
    __syncthreads();
    if (tid < 256) {  // 8-way K-reduce + LSTM cell 0
      float gg[4];
#pragma unroll
      for (int g = 0; g < 4; ++g) {
        float v = bias0[g];
#pragma unroll
        for (int ww = 0; ww < 8; ++ww) v += red[ww][(u_l << 2) + g][bq];
        gg[g] = v;
      }
      float cn = sigm(gg[1]) * c0v + sigm(gg[0]) * tanhf(gg[2]);
      c0v = cn;
      float hn = sigm(gg[3]) * tanhf(cn);
      vstore_bf16(h0buf + ((size_t)((t + 1) & 1) << 16) + ((size_t)bq << 10) +
                      (cb >> 2) + u_l,
                  hn);
    }

    // ---- single barrier: publishes h0[t] (phase A) and h1[t-1] (B_{t-1}) --
    bar_arrive(bar, lvl, t, tid);
    // proj h1[t-2] -> out[t-2] in the stall window: published at bar(t-1),
    // L1-resident (B_{t-1} read it), next overwritten only in B_{t+1}.
    if (isproj && t >= 2)
      do_proj(h1proj, wp, red, blin, out, bid, t - 2, tid, w, col, kq);
    bar_wait(bar, t, tid);

    // ======== phase B: gates1 = [h0cur | h1prev] @ W1^T ========
    {
      const __hip_bfloat16* ab =
          ((w < 4) ? h0cur : h1prev) + ((w & 3) << 8) + (kq << 3);
      f32x4 a0 = {0.f, 0.f, 0.f, 0.f}, a1 = a0, a2 = a0, a3 = a0;
#pragma unroll
      for (int c = 0; c < 8; ++c) {
        const __hip_bfloat16* p = ab + (c << 5);
        bf16x8 f0 = *(const bf16x8*)(p + ((size_t)col << 10));
        bf16x8 f1 = *(const bf16x8*)(p + ((size_t)(16 + col) << 10));
        bf16x8 f2 = *(const bf16x8*)(p + ((size_t)(32 + col) << 10));
        bf16x8 f3 = *(const bf16x8*)(p + ((size_t)(48 + col) << 10));
        a0 = __builtin_amdgcn_mfma_f32_16x16x32_bf16(f0, wb[c], a0, 0, 0, 0);
        a1 = __builtin_amdgcn_mfma_f32_16x16x32_bf16(f1, wb[c], a1, 0, 0, 0);
        a2 = __builtin_amdgcn_mfma_f32_16x16x32_bf16(f2, wb[c], a2, 0, 0, 0);
        a3 = __builtin_amdgcn_mfma_f32_16x16x32_bf16(f3, wb[c], a3, 0, 0, 0);
      }
      *(f32x4*)&red[w][col][(kq << 2)] = a0;
      *(f32x4*)&red[w][col][16 + (kq << 2)] = a1;
      *(f32x4*)&red[w][col][32 + (kq << 2)] = a2;
      *(f32x4*)&red[w][col][48 + (kq << 2)] = a3;
    }
    __syncthreads();
    if (tid < 256) {  // 8-way K-reduce + LSTM cell 1
      float gg[4];
#pragma unroll
      for (int g = 0; g < 4; ++g) {
        float v = bias1[g];
#pragma unroll
        for (int ww = 0; ww < 8; ++ww) v += red[ww][(u_l << 2) + g][bq];
        gg[g] = v;
      }
      float cn = sigm(gg[1]) * c1v + sigm(gg[0]) * tanhf(gg[2]);
      c1v = cn;
      float hn = sigm(gg[3]) * tanhf(cn);
      vstore_bf16(h1buf + ((size_t)(t % 3) << 16) + ((size_t)bq << 10) +
                      (cb >> 2) + u_l,
                  hn);
    }
    __syncthreads();  // red safe for next iteration's phase A
  }

  // final barrier publishes h1[511]; project tail out[510], out[511]
  bar_arrive(bar, lvl, 512, tid);
  bar_wait(bar, 512, tid);
  if (isproj) {
    do_proj(h1buf + ((size_t)(510 % 3) << 16), wp, red, blin, out, bid, 510,
            tid, w, col, kq);
    do_proj(h1buf + ((size_t)(511 % 3) << 16), wp, red, blin, out, bid, 511,
            tid, w, col, kq);
  }
}

// ---------------- host launch ----------------

extern "C" void kernel_launch(void* const* d_in, const int* in_sizes, int n_in,
                              void* d_out, int out_size, void* d_ws, size_t ws_size,
                              hipStream_t stream) {
  const float* z = (const float*)d_in[0];
  const float* x = (const float*)d_in[1];
  const float* Wih0 = (const float*)d_in[2];
  const float* Whh0 = (const float*)d_in[3];
  const float* bih0 = (const float*)d_in[4];
  const float* bhh0 = (const float*)d_in[5];
  const float* Wih1 = (const float*)d_in[6];
  const float* Whh1 = (const float*)d_in[7];
  const float* bih1 = (const float*)d_in[8];
  const float* bhh1 = (const float*)d_in[9];
  const float* Wlin = (const float*)d_in[10];
  const float* blin = (const float*)d_in[11];
  float* out = (float*)d_out;

  char* ws = (char*)d_ws;
  __hip_bfloat16* W0 = (__hip_bfloat16*)(ws);                // 10,485,760 B
  __hip_bfloat16* W1 = (__hip_bfloat16*)(ws + 10485760);     // 17,825,792 B
  __hip_bfloat16* xbf = (__hip_bfloat16*)(ws + 28311552);    // 16,777,216 B
  float* b0 = (float*)(ws + 45088768);                       // 16,384 B
  float* b1 = (float*)(ws + 45105152);                       // 16,384 B
  __hip_bfloat16* h0buf = (__hip_bfloat16*)(ws + 45121536);  // 262,144 B (2 slots)
  __hip_bfloat16* h1buf = (__hip_bfloat16*)(ws + 45383680);  // 393,216 B (3 slots)
  unsigned* bar = (unsigned*)(ws + 45776896);                // 4,096 B

  hipMemsetAsync(bar, 0, 4096, stream);  // ws is re-poisoned every call
  prep_w0<<<4096, 256, 0, stream>>>(Wih0, Whh0, W0);
  prep_w1<<<4096, 256, 0, stream>>>(Wih1, Whh1, Wlin, W1);
  prep_x<<<4096, 256, 0, stream>>>(x, xbf);
  prep_misc<<<288, 256, 0, stream>>>(bih0, bhh0, bih1, bhh1, z, b0, b1, h0buf,
                                     h1buf);

  k_persist<<<256, 512, 0, stream>>>(xbf, W0, W1, b0, b1, blin, h0buf, h1buf,
                                     out, bar);
}